// Round 9
// baseline (333.071 us; speedup 1.0000x reference)
//
#include <hip/hip_runtime.h>
#include <hip/hip_bf16.h>
#include <math.h>

#define B_ 8
#define W_ 1024
#define D_ 1024
#define R_ 64

typedef __hip_bfloat16 bf16;
typedef __attribute__((ext_vector_type(8))) short bf16x8;   // MFMA A/B frag (4 VGPRs)
typedef __attribute__((ext_vector_type(4))) short short4v;  // 4 bf16 store
typedef __attribute__((ext_vector_type(4))) float f32x4;    // MFMA C/D frag

__device__ __forceinline__ float tof(bf16 x) { return __bfloat162float(x); }
__device__ __forceinline__ short f2bs(float f) {
    bf16 b = __float2bfloat16(f);
    return *(short*)&b;
}

// async global->LDS, 16 bytes/lane; LDS dest = wave-uniform base + lane*16
__device__ __forceinline__ void async16(const void* g, void* l) {
    __builtin_amdgcn_global_load_lds(
        (const __attribute__((address_space(1))) unsigned int*)g,
        (__attribute__((address_space(3))) unsigned int*)l,
        16, 0, 0);
}

// ---------------------------------------------------------------------------
// RMSNorm body (float4-vectorized): row of D_=1024, 256 threads.
// ---------------------------------------------------------------------------
__device__ __forceinline__ void rmsnorm_body(const float* __restrict__ src,
                                             const float* __restrict__ scale,
                                             bf16* __restrict__ dst, int row,
                                             float* red, float* invs) {
    const float4* x = (const float4*)(src + (size_t)row * D_);
    bf16* y = dst + (size_t)row * D_;
    int t = threadIdx.x;
    float4 v = x[t];
    float ss = v.x * v.x + v.y * v.y + v.z * v.z + v.w * v.w;
#pragma unroll
    for (int off = 32; off; off >>= 1) ss += __shfl_down(ss, off, 64);
    int lane = t & 63, wid = t >> 6;
    if (lane == 0) red[wid] = ss;
    __syncthreads();
    if (t == 0) {
        float s = red[0] + red[1] + red[2] + red[3];
        *invs = rsqrtf(s / (float)D_ + 1e-8f);
    }
    __syncthreads();
    float inv = *invs;
    float4 s4 = ((const float4*)scale)[t];
    short4v o;
    o[0] = f2bs(v.x * inv * s4.x);
    o[1] = f2bs(v.y * inv * s4.y);
    o[2] = f2bs(v.z * inv * s4.z);
    o[3] = f2bs(v.w * inv * s4.w);
    *(short4v*)&y[t * 4] = o;
}

__global__ __launch_bounds__(256)
void rmsnorm_kernel(const float* __restrict__ src, const float* __restrict__ scale,
                    bf16* __restrict__ dst) {
    __shared__ float red[4];
    __shared__ float invs;
    rmsnorm_body(src, scale, dst, blockIdx.x, red, &invs);
}

// ---------------------------------------------------------------------------
// prep_kernel: ONE launch fusing three independent prep ops.
//  blocks [0, 2560)      : fp32->bf16 convert of proj/up/down weights
//  blocks [2560, 2592)   : uvT build ([128][1024] bf16 from u,v [1024][64])
//  blocks [2592, 10784)  : rmsnorm(h) -> hnorm
// ---------------------------------------------------------------------------
__global__ __launch_bounds__(256)
void prep_kernel(const float* __restrict__ proj, const float* __restrict__ up,
                 const float* __restrict__ down,
                 bf16* __restrict__ projb, bf16* __restrict__ upb,
                 bf16* __restrict__ downb,
                 const float* __restrict__ u, const float* __restrict__ v,
                 bf16* __restrict__ uvT,
                 const float* __restrict__ h, const float* __restrict__ n1,
                 bf16* __restrict__ hnorm) {
    __shared__ float Ts[64][65];
    __shared__ float red[4];
    __shared__ float invs;
    int bid = blockIdx.x;
    int tid = threadIdx.x;
    if (bid < 2560) {
        // ---- convert3 ----
        size_t idx = ((size_t)bid * 256 + tid) * 8;
        const size_t DD = (size_t)D_ * D_;
        const float* src; bf16* dst; size_t off;
        if (idx < DD)          { src = proj; dst = projb; off = idx; }
        else if (idx < 3 * DD) { src = up;   dst = upb;   off = idx - DD; }
        else                   { src = down; dst = downb; off = idx - 3 * DD; }
        float4 f0 = *(const float4*)(src + off);
        float4 f1 = *(const float4*)(src + off + 4);
        bf16x8 p;
        p[0] = f2bs(f0.x); p[1] = f2bs(f0.y); p[2] = f2bs(f0.z); p[3] = f2bs(f0.w);
        p[4] = f2bs(f1.x); p[5] = f2bs(f1.y); p[6] = f2bs(f1.z); p[7] = f2bs(f1.w);
        *(bf16x8*)(dst + off) = p;
    } else if (bid < 2592) {
        // ---- uvT ----
        int lb = bid - 2560;
        int g = lb >> 4;
        int d0 = (lb & 15) * 64;
        const float* src = g ? v : u;
#pragma unroll
        for (int e = 0; e < 16; ++e) {
            int idx = tid + e * 256;
            int drow = idx >> 6, rcol = idx & 63;
            Ts[drow][rcol] = src[(size_t)(d0 + drow) * 64 + rcol];
        }
        __syncthreads();
#pragma unroll
        for (int e = 0; e < 16; ++e) {
            int idx = tid + e * 256;
            int orow = idx >> 6, ocol = idx & 63;
            uvT[(size_t)(g * 64 + orow) * D_ + d0 + ocol] = __float2bfloat16(Ts[ocol][orow]);
        }
    } else {
        // ---- rmsnorm(h) ----
        rmsnorm_body(h, n1, hnorm, bid - 2592, red, &invs);
    }
}

// ---------------------------------------------------------------------------
// 64x64 LDS-tiled transpose: src[b][j][d] -> dst[b][d][j]  (bf16)
// ---------------------------------------------------------------------------
__global__ __launch_bounds__(256)
void transpose_kernel(const bf16* __restrict__ src, bf16* __restrict__ dst) {
    int b = blockIdx.z;
    int j0 = blockIdx.x * 64, d0 = blockIdx.y * 64;
    __shared__ short Ts[64][72];
    const bf16* S = src + (size_t)b * W_ * D_;
    bf16* Dd = dst + (size_t)b * W_ * D_;
    int tid = threadIdx.x;
    int r = tid >> 3, c = (tid & 7) * 8;
#pragma unroll
    for (int p = 0; p < 2; ++p) {
        int j = r + p * 32;
        bf16x8 vv = *(const bf16x8*)&S[(size_t)(j0 + j) * D_ + d0 + c];
#pragma unroll
        for (int e = 0; e < 8; ++e) Ts[j][c + e] = vv[e];
    }
    __syncthreads();
#pragma unroll
    for (int p = 0; p < 2; ++p) {
        int d = r + p * 32;
        bf16x8 vv;
#pragma unroll
        for (int e = 0; e < 8; ++e) vv[e] = Ts[c + e][d];
        *(bf16x8*)&Dd[(size_t)(d0 + d) * W_ + j0 + c] = vv;
    }
}

// ---------------------------------------------------------------------------
// qk epilogue: sum SK=4 fp32 partials, l2norm halves, gamma^{+/-i} -> qg, kg.
// ---------------------------------------------------------------------------
__global__ __launch_bounds__(128)
void qk_epilogue_kernel(const float* __restrict__ qkraw,
                        const float* __restrict__ decay_logit,
                        float* __restrict__ qg, float* __restrict__ kg) {
    int row = blockIdx.x;          // b*W + i
    int i = row & (W_ - 1);
    int t = threadIdx.x;
    int r = t & 63;
    bool isK = t >= 64;
    const size_t PS = (size_t)B_ * W_ * 128;   // partial stride
    size_t off = (size_t)row * 128 + t;
    float val = qkraw[off] + qkraw[PS + off] + qkraw[2 * PS + off] + qkraw[3 * PS + off];
    float sq = val * val;
#pragma unroll
    for (int o = 32; o; o >>= 1) sq += __shfl_xor(sq, o, 64);
    val = val / fmaxf(sqrtf(sq), 1e-8f);

    float dl = decay_logit[r];
    float gamma = 0.15f + 0.85f * (1.f / (1.f + expf(-dl)));
    float lg = logf(gamma);
    float e = isK ? expf(-(float)i * lg) : expf((float)i * lg);
    float o = val * e;
    if (isK) kg[(size_t)row * R_ + r] = o;
    else     qg[(size_t)row * R_ + r] = o;
}

// ---------------------------------------------------------------------------
// buildM v2: M[b,i,j] = (j<=i) ? gate*k_base + alpha*qg.kg : 0
// 64x64 tiles, float4 LDS reads, skip-without-write tiles tj > (ti|1)
// (provably unread by step 4's causal k-truncation).
// ---------------------------------------------------------------------------
__global__ __launch_bounds__(256)
void buildM_kernel(const float* __restrict__ qg, const float* __restrict__ kg,
                   const float* __restrict__ k_base,
                   const float* __restrict__ gate_logit,
                   const float* __restrict__ alpha_logit,
                   bf16* __restrict__ M) {
    int b = blockIdx.z;
    int ti = blockIdx.y, tj = blockIdx.x;   // 64-row/col tiles
    if (tj > (ti | 1)) return;              // never read by step 4: no write
    int i0 = ti * 64, j0 = tj * 64;
    bf16* Mb = M + (size_t)b * W_ * W_;
    int tid = threadIdx.x;

    if (tj > ti) {
        int row = tid >> 2, c0 = (tid & 3) * 16;
        bf16x8 z;
#pragma unroll
        for (int e = 0; e < 8; ++e) z[e] = 0;
        *(bf16x8*)&Mb[(size_t)(i0 + row) * W_ + j0 + c0] = z;
        *(bf16x8*)&Mb[(size_t)(i0 + row) * W_ + j0 + c0 + 8] = z;
        return;
    }

    __shared__ float Qs[64][68];
    __shared__ float Ks[64][68];
#pragma unroll
    for (int e = 0; e < 4; ++e) {
        int idx = tid + e * 256;            // float4 slot 0..1023
        int row = idx >> 4, c4 = (idx & 15) * 4;
        *(float4*)&Qs[row][c4] = *(const float4*)&qg[((size_t)b * W_ + i0 + row) * R_ + c4];
        *(float4*)&Ks[row][c4] = *(const float4*)&kg[((size_t)b * W_ + j0 + row) * R_ + c4];
    }
    __syncthreads();

    int tx = tid & 15, ty = tid >> 4;       // 4 cols, 4 rows per thread
    float acc[4][4] = {};
#pragma unroll 4
    for (int rq = 0; rq < 16; ++rq) {
        float4 qa[4], kb[4];
#pragma unroll
        for (int a = 0; a < 4; ++a) qa[a] = *(const float4*)&Qs[ty * 4 + a][rq * 4];
#pragma unroll
        for (int c = 0; c < 4; ++c) kb[c] = *(const float4*)&Ks[tx * 4 + c][rq * 4];
#pragma unroll
        for (int a = 0; a < 4; ++a)
#pragma unroll
            for (int c = 0; c < 4; ++c)
                acc[a][c] += qa[a].x * kb[c].x + qa[a].y * kb[c].y
                           + qa[a].z * kb[c].z + qa[a].w * kb[c].w;
    }

    float gate  = 1.f / (1.f + expf(-(*gate_logit)));
    float alpha = 1.f / (1.f + expf(-(*alpha_logit)));  // ALPHA_CAP = 1
#pragma unroll
    for (int a = 0; a < 4; ++a) {
        int i = i0 + ty * 4 + a;
        int jb = j0 + tx * 4;
        float4 vkb = *(const float4*)&k_base[(size_t)i * W_ + jb];
        short4v o;
        o[0] = (jb + 0 <= i) ? f2bs(gate * vkb.x + alpha * acc[a][0]) : (short)0;
        o[1] = (jb + 1 <= i) ? f2bs(gate * vkb.y + alpha * acc[a][1]) : (short)0;
        o[2] = (jb + 2 <= i) ? f2bs(gate * vkb.z + alpha * acc[a][2]) : (short)0;
        o[3] = (jb + 3 <= i) ? f2bs(gate * vkb.w + alpha * acc[a][3]) : (short)0;
        *(short4v*)&Mb[(size_t)i * W_ + jb] = o;
    }
}

// ---------------------------------------------------------------------------
// shared GEMM helpers
// ---------------------------------------------------------------------------
#define BAR() do { __builtin_amdgcn_sched_barrier(0); \
                   __builtin_amdgcn_s_barrier(); \
                   __builtin_amdgcn_sched_barrier(0); } while (0)

__device__ __forceinline__ void mfma8(const bf16x8 (&fa)[2], const bf16x8 (&fb)[4],
                                      f32x4 (&acc)[2][4]) {
#pragma unroll
    for (int mi = 0; mi < 2; ++mi)
#pragma unroll
        for (int ni = 0; ni < 4; ++ni)
            acc[mi][ni] = __builtin_amdgcn_mfma_f32_16x16x32_bf16(
                fa[mi], fb[ni], acc[mi][ni], 0, 0, 0);
}

__device__ __forceinline__ void readf(const short* At0, const short* Bt0, int slot,
                                      const int (&ao)[2], const int (&bo)[4],
                                      bf16x8 (&fa)[2], bf16x8 (&fb)[4]) {
    const short* Ard = At0 + slot * 4096;
    const short* Brd = Bt0 + slot * 4096;
#pragma unroll
    for (int mi = 0; mi < 2; ++mi) fa[mi] = *(const bf16x8*)&Ard[ao[mi]];
#pragma unroll
    for (int ni = 0; ni < 4; ++ni) fb[ni] = *(const bf16x8*)&Brd[bo[ni]];
}

// ---------------------------------------------------------------------------
// 128x128 8-wave MFMA GEMM, 5-slot ring — r15 geometry (proven best:
// tile/waves/swizzle/staging/epilogue unchanged since r15).
// *** Round-21 change: PAIR LOOP — one vmcnt + one barrier per TWO K-tiles.
// Evidence r15-r20: per block-iter ~1119 cyc vs component floors MFMA 310 /
// ds_read ~260 / staging ~270 (all pipes <=30%); the residual ~550cyc/iter
// is the per-iteration sync envelope (vmcnt wait + barrier convoy), paid
// 2x per 64 K. Halve its frequency, keep everything else:
//   pair p: vmcnt(0) [pair p's 4 loads, issued one pair-body (~1500cyc)
//           earlier -> latency covered] | BAR [publishes tiles 2p,2p+1] |
//           stage pair p+1 (tiles 2p+2,2p+3) | read+mfma tile 2p |
//           read+mfma tile 2p+1.
// Slot audit (tile t -> slot t%5): stage targets (2p+2)%5 held tile 2p-3
// (read pair p-2, two barriers ago) and (2p+3)%5 held tile 2p-2 (read pair
// p-1, one barrier ago — all waves passed this pair's BAR since) — safe;
// stage slots differ from read slots by 2 mod 5 != 0 — no self-collision.
// Block-wide publish: each wave's vmcnt(0) covers its OWN staging loads
// (disjoint LDS regions; union = whole tiles), barrier publishes (r14 inv).
// nIter even >= 4 at all call sites (K mult of 128; SK chunk 256).
// r20 causal stripe-mirror kept (balanced 36 block-iters/CU on step 4).
// EPI 0: bf16 = acc (batched via z*sC) | EPI 1: fp32 = acc+bias+Res |
// EPI 2: bf16 = gelu(acc+bias)         | EPI 5: fp32 partial at z*sC.
// ---------------------------------------------------------------------------
template<int EPI, int SK>
__global__ __launch_bounds__(512, 4)
void mgemm_kernel(const bf16* __restrict__ A, const bf16* __restrict__ Bm,
                  const float* __restrict__ Res, const float* __restrict__ bias,
                  void* __restrict__ Cout,
                  int M, int N, int K,
                  long sA, long sB, long sC, int causal) {
    __shared__ __align__(16) short At[5][128 * 32];
    __shared__ __align__(16) short Bt[5][128 * 32];
    int z = blockIdx.z;
    const bf16* Ab = (SK > 1) ? A : A + (size_t)z * sA;
    const bf16* Bb = (SK > 1) ? Bm : Bm + (size_t)z * sB;
    int kchunk = K / SK;
    int kbeg = (SK > 1) ? z * kchunk : 0;
    int bx = blockIdx.x;
    if (SK == 1 && causal && z >= (int)(gridDim.z >> 1))
        bx = (int)gridDim.x - 1 - bx;        // r20: mirror stripe, balance pair
    int m0 = bx * 128, n0 = blockIdx.y * 128;
    int tid = threadIdx.x;
    int lane = tid & 63, wave = tid >> 6;
    int wy = wave >> 1, wx = wave & 1;
    int quad = lane >> 4, l15 = lane & 15;

    f32x4 acc[2][4];
#pragma unroll
    for (int i = 0; i < 2; ++i)
#pragma unroll
        for (int j = 0; j < 4; ++j)
            acc[i][j] = (f32x4){0.f, 0.f, 0.f, 0.f};

    int kend = kbeg + kchunk;
    if (SK == 1 && causal) kend = (m0 + 128 < K) ? m0 + 128 : K;
    int nIter = (kend - kbeg) >> 5;          // even, >= 4
    int P = nIter >> 1;                      // pairs

    int srcChunk = ((lane & 3) ^ ((lane >> 3) & 3)) * 8;
    size_t rowA = (size_t)(m0 + wave * 16 + (lane >> 2)) * K;
    size_t rowB = (size_t)(n0 + wave * 16 + (lane >> 2)) * K;
    const bf16* aP = Ab + rowA + srcChunk + kbeg;
    const bf16* bP = Bb + rowB + srcChunk + kbeg;
    short* aDst = &At[0][0] + wave * 512;
    short* bDst = &Bt[0][0] + wave * 512;

    int rswz = (quad ^ ((l15 >> 1) & 3)) * 8;
    int ao[2], bo[4];
#pragma unroll
    for (int mi = 0; mi < 2; ++mi) ao[mi] = (wy * 32 + mi * 16 + l15) * 32 + rswz;
#pragma unroll
    for (int ni = 0; ni < 4; ++ni) bo[ni] = (wx * 64 + ni * 16 + l15) * 32 + rswz;

    // prologue: stage pair 0 (tiles 0,1 -> slots 0,1); loop's vmcnt(0) waits it
    async16(aP, aDst);          async16(bP, bDst);          aP += 32; bP += 32;
    async16(aP, aDst + 4096);   async16(bP, bDst + 4096);   aP += 32; bP += 32;

    int sStage = 2;   // slot for next staged tile (tile 2)
    int sCur = 0;     // slot of tile 2p
    bf16x8 fa0[2], fb0[4], fa1[2], fb1[4];

    for (int p = 0; p < P; ++p) {
        asm volatile("s_waitcnt vmcnt(0)" ::: "memory");
        BAR();                               // publishes tiles 2p, 2p+1
        if (p + 1 < P) {                     // stage pair p+1
            async16(aP, aDst + sStage * 4096);
            async16(bP, bDst + sStage * 4096);
            aP += 32; bP += 32;
            sStage = (sStage == 4) ? 0 : sStage + 1;
            async16(aP, aDst + sStage * 4096);
            async16(bP, bDst + sStage * 4096);
            aP += 32; bP += 32;
            sStage = (sStage == 4) ? 0 : sStage + 1;
        }
        readf(&At[0][0], &Bt[0][0], sCur, ao, bo, fa0, fb0);
        mfma8(fa0, fb0, acc);
        sCur = (sCur == 4) ? 0 : sCur + 1;
        readf(&At[0][0], &Bt[0][0], sCur, ao, bo, fa1, fb1);
        mfma8(fa1, fb1, acc);
        sCur = (sCur == 4) ? 0 : sCur + 1;
    }

    // ---- epilogue ----
#pragma unroll
    for (int ni = 0; ni < 4; ++ni) {
        int col = n0 + wx * 64 + ni * 16 + l15;
        float bv = (EPI == 1 || EPI == 2) ? bias[col] : 0.f;
#pragma unroll
        for (int mi = 0; mi < 2; ++mi) {
            int row0 = m0 + wy * 32 + mi * 16 + quad * 4;
#pragma unroll
            for (int r = 0; r < 4; ++r) {
                size_t idx = (size_t)(row0 + r) * N + col;
                float val = acc[mi][ni][r];
                if constexpr (EPI == 0) {
                    ((bf16*)Cout)[(size_t)z * sC + idx] = __float2bfloat16(val);
                } else if constexpr (EPI == 1) {
                    ((float*)Cout)[idx] = val + bv + Res[idx];
                } else if constexpr (EPI == 2) {
                    val += bv;
                    val = 0.5f * val * (1.f + erff(val * 0.70710678118654752f));
                    ((bf16*)Cout)[idx] = __float2bfloat16(val);
                } else {
                    ((float*)Cout)[(size_t)z * sC + idx] = val;
                }
            }
        }
    }
}

// ---------------------------------------------------------------------------
// Workspace (peak 62 MB):
//   [0,16)  : hnorm bf16 -> attn bf16 (step4 out) -> mnorm bf16 (step6 out)
//   [16,18) : uvT bf16 (dead after step 2) -> qg fp32 (written step 2b)
//   [18,20) : kg fp32
//   [20,36) : hnormT bf16            -+ tbuf bf16 [20,52) after step 4
//   [36,52) : qkraw fp32 4x4MB split-K partials (dead after 2b) -> Mbuf bf16
//   [52,54) : proj_w bf16   [54,58): up_w bf16   [58,62): down_w bf16
//   h1 lives in d_out (fp32); step 8 does same-index RMW (alias-safe).
// ---------------------------------------------------------------------------
extern "C" void kernel_launch(void* const* d_in, const int* in_sizes, int n_in,
                              void* d_out, int out_size, void* d_ws, size_t ws_size,
                              hipStream_t stream) {
    const float* h           = (const float*)d_in[0];
    const float* k_base      = (const float*)d_in[1];
    const float* decay_logit = (const float*)d_in[2];
    const float* gate_logit  = (const float*)d_in[3];
    const float* alpha_logit = (const float*)d_in[4];
    const float* u           = (const float*)d_in[5];
    const float* v           = (const float*)d_in[6];
    const float* proj_w      = (const float*)d_in[7];
    const float* proj_b      = (const float*)d_in[8];
    const float* norm1_scale = (const float*)d_in[9];
    const float* norm2_scale = (const float*)d_in[10];
    const float* up_w        = (const float*)d_in[11];
    const float* up_b        = (const float*)d_in[12];
    const float* down_w      = (const float*)d_in[13];
    const float* down_b      = (const float*)d_in[14];

    const size_t MB = 1048576;
    char* ws = (char*)d_ws;
    bf16*  hnorm   = (bf16*)(ws);                  // 16 MB
    bf16*  uvT     = (bf16*)(ws + 16 * MB);        // 256 KB (dead after step 2)
    float* qg      = (float*)(ws + 16 * MB);       //  2 MB (written step 2b)
    float* kg      = (float*)(ws + 18 * MB);       //  2 MB
    bf16*  hnormT  = (bf16*)(ws + 20 * MB);        // 16 MB
    float* qkraw   = (float*)(ws + 36 * MB);       // 16 MB partials (pre-buildM)
    bf16*  Mbuf    = (bf16*)(ws + 36 * MB);        // 16 MB (step 3 out)
    bf16*  proj_wb = (bf16*)(ws + 52 * MB);        //  2 MB
    bf16*  up_wb   = (bf16*)(ws + 54 * MB);        //  4 MB
    bf16*  down_wb = (bf16*)(ws + 58 * MB);        //  4 MB
    bf16*  attn    = hnorm;                        // [0,16) after qk GEMM
    bf16*  mnorm   = hnorm;
    bf16*  tbuf    = hnormT;                       // [20,52) after step 4
    float* h1      = (float*)d_out;

    // 0+1. fused prep: weight converts + uvT + rmsnorm(h) in ONE launch
    prep_kernel<<<2560 + 32 + B_ * W_, 256, 0, stream>>>(
        proj_w, up_w, down_w, proj_wb, up_wb, down_wb,
        u, v, uvT, h, norm1_scale, hnorm);

    // 1b. hnormT[b][d][j] = hnorm[b][j][d]
    transpose_kernel<<<dim3(W_ / 64, D_ / 64, B_), 256, 0, stream>>>(hnorm, hnormT);

    // 2. qkraw[z] = hnorm @ [u|v] K-chunk z (deterministic split-K=4)
    mgemm_kernel<5, 4><<<dim3(B_ * W_ / 128, 1, 4), 512, 0, stream>>>(
        hnorm, uvT, nullptr, nullptr, qkraw, B_ * W_, 128, D_,
        0, 0, (long)B_ * W_ * 128, 0);

    // 2b. sum partials, l2norm halves, gamma^{+/-i} -> qg, kg (fp32)
    qk_epilogue_kernel<<<B_ * W_, 128, 0, stream>>>(qkraw, decay_logit, qg, kg);

    // 3. M = causal * (gate*k_base + alpha*scores)  [64x64 tiles, skip-unread]
    buildM_kernel<<<dim3(W_ / 64, W_ / 64, B_), 256, 0, stream>>>(
        qg, kg, k_base, gate_logit, alpha_logit, Mbuf);

    // 4. attn = M @ hnorm  (B = hnormT, batched via z, causal k-trunc,
    //    stripe-mirrored for z>=4: per-CU work balanced at 36 block-iters)
    mgemm_kernel<0, 1><<<dim3(W_ / 128, D_ / 128, B_), 512, 0, stream>>>(
        Mbuf, hnormT, nullptr, nullptr, attn, W_, D_, W_,
        (long)W_ * W_, (long)W_ * D_, (long)W_ * D_, 1);

    // 5. h1 = h + attn @ proj_w^T + proj_b   -> d_out (fp32)
    mgemm_kernel<1, 1><<<dim3(B_ * W_ / 128, D_ / 128, 1), 512, 0, stream>>>(
        attn, proj_wb, h, proj_b, h1, B_ * W_, D_, D_, 0, 0, 0, 0);

    // 6. mnorm = rmsnorm(h1, norm2_scale)
    rmsnorm_kernel<<<B_ * W_, 256, 0, stream>>>(h1, norm2_scale, mnorm);

    // 7. t = gelu(mnorm @ up_w^T + up_b)     -> tbuf (bf16)
    mgemm_kernel<2, 1><<<dim3(B_ * W_ / 128, 2 * D_ / 128, 1), 512, 0, stream>>>(
        mnorm, up_wb, nullptr, up_b, tbuf, B_ * W_, 2 * D_, D_, 0, 0, 0, 0);

    // 8. out = h1 + t @ down_w^T + down_b  (h1 aliases d_out, same-idx RMW)
    mgemm_kernel<1, 1><<<dim3(B_ * W_ / 128, D_ / 128, 1), 512, 0, stream>>>(
        tbuf, down_wb, h1, down_b, (float*)d_out, B_ * W_, D_, 2 * D_, 0, 0, 0, 0);
}

// Round 10
// 323.622 us; speedup vs baseline: 1.0292x; 1.0292x over previous
//
#include <hip/hip_runtime.h>
#include <hip/hip_bf16.h>
#include <math.h>

#define B_ 8
#define W_ 1024
#define D_ 1024
#define R_ 64

typedef __hip_bfloat16 bf16;
typedef __attribute__((ext_vector_type(8))) short bf16x8;   // MFMA A/B frag (4 VGPRs)
typedef __attribute__((ext_vector_type(4))) short short4v;  // 4 bf16 store
typedef __attribute__((ext_vector_type(4))) float f32x4;    // MFMA C/D frag

__device__ __forceinline__ float tof(bf16 x) { return __bfloat162float(x); }
__device__ __forceinline__ short f2bs(float f) {
    bf16 b = __float2bfloat16(f);
    return *(short*)&b;
}

// async global->LDS, 16 bytes/lane; LDS dest = wave-uniform base + lane*16
__device__ __forceinline__ void async16(const void* g, void* l) {
    __builtin_amdgcn_global_load_lds(
        (const __attribute__((address_space(1))) unsigned int*)g,
        (__attribute__((address_space(3))) unsigned int*)l,
        16, 0, 0);
}

// ---------------------------------------------------------------------------
// RMSNorm body (float4-vectorized): row of D_=1024, 256 threads.
// ---------------------------------------------------------------------------
__device__ __forceinline__ void rmsnorm_body(const float* __restrict__ src,
                                             const float* __restrict__ scale,
                                             bf16* __restrict__ dst, int row,
                                             float* red, float* invs) {
    const float4* x = (const float4*)(src + (size_t)row * D_);
    bf16* y = dst + (size_t)row * D_;
    int t = threadIdx.x;
    float4 v = x[t];
    float ss = v.x * v.x + v.y * v.y + v.z * v.z + v.w * v.w;
#pragma unroll
    for (int off = 32; off; off >>= 1) ss += __shfl_down(ss, off, 64);
    int lane = t & 63, wid = t >> 6;
    if (lane == 0) red[wid] = ss;
    __syncthreads();
    if (t == 0) {
        float s = red[0] + red[1] + red[2] + red[3];
        *invs = rsqrtf(s / (float)D_ + 1e-8f);
    }
    __syncthreads();
    float inv = *invs;
    float4 s4 = ((const float4*)scale)[t];
    short4v o;
    o[0] = f2bs(v.x * inv * s4.x);
    o[1] = f2bs(v.y * inv * s4.y);
    o[2] = f2bs(v.z * inv * s4.z);
    o[3] = f2bs(v.w * inv * s4.w);
    *(short4v*)&y[t * 4] = o;
}

__global__ __launch_bounds__(256)
void rmsnorm_kernel(const float* __restrict__ src, const float* __restrict__ scale,
                    bf16* __restrict__ dst) {
    __shared__ float red[4];
    __shared__ float invs;
    rmsnorm_body(src, scale, dst, blockIdx.x, red, &invs);
}

// ---------------------------------------------------------------------------
// prep_kernel: ONE launch fusing three independent prep ops.
//  blocks [0, 2560)      : fp32->bf16 convert of proj/up/down weights
//  blocks [2560, 2592)   : uvT build ([128][1024] bf16 from u,v [1024][64])
//  blocks [2592, 10784)  : rmsnorm(h) -> hnorm
// ---------------------------------------------------------------------------
__global__ __launch_bounds__(256)
void prep_kernel(const float* __restrict__ proj, const float* __restrict__ up,
                 const float* __restrict__ down,
                 bf16* __restrict__ projb, bf16* __restrict__ upb,
                 bf16* __restrict__ downb,
                 const float* __restrict__ u, const float* __restrict__ v,
                 bf16* __restrict__ uvT,
                 const float* __restrict__ h, const float* __restrict__ n1,
                 bf16* __restrict__ hnorm) {
    __shared__ float Ts[64][65];
    __shared__ float red[4];
    __shared__ float invs;
    int bid = blockIdx.x;
    int tid = threadIdx.x;
    if (bid < 2560) {
        // ---- convert3 ----
        size_t idx = ((size_t)bid * 256 + tid) * 8;
        const size_t DD = (size_t)D_ * D_;
        const float* src; bf16* dst; size_t off;
        if (idx < DD)          { src = proj; dst = projb; off = idx; }
        else if (idx < 3 * DD) { src = up;   dst = upb;   off = idx - DD; }
        else                   { src = down; dst = downb; off = idx - 3 * DD; }
        float4 f0 = *(const float4*)(src + off);
        float4 f1 = *(const float4*)(src + off + 4);
        bf16x8 p;
        p[0] = f2bs(f0.x); p[1] = f2bs(f0.y); p[2] = f2bs(f0.z); p[3] = f2bs(f0.w);
        p[4] = f2bs(f1.x); p[5] = f2bs(f1.y); p[6] = f2bs(f1.z); p[7] = f2bs(f1.w);
        *(bf16x8*)(dst + off) = p;
    } else if (bid < 2592) {
        // ---- uvT ----
        int lb = bid - 2560;
        int g = lb >> 4;
        int d0 = (lb & 15) * 64;
        const float* src = g ? v : u;
#pragma unroll
        for (int e = 0; e < 16; ++e) {
            int idx = tid + e * 256;
            int drow = idx >> 6, rcol = idx & 63;
            Ts[drow][rcol] = src[(size_t)(d0 + drow) * 64 + rcol];
        }
        __syncthreads();
#pragma unroll
        for (int e = 0; e < 16; ++e) {
            int idx = tid + e * 256;
            int orow = idx >> 6, ocol = idx & 63;
            uvT[(size_t)(g * 64 + orow) * D_ + d0 + ocol] = __float2bfloat16(Ts[ocol][orow]);
        }
    } else {
        // ---- rmsnorm(h) ----
        rmsnorm_body(h, n1, hnorm, bid - 2592, red, &invs);
    }
}

// ---------------------------------------------------------------------------
// 64x64 LDS-tiled transpose: src[b][j][d] -> dst[b][d][j]  (bf16)
// ---------------------------------------------------------------------------
__global__ __launch_bounds__(256)
void transpose_kernel(const bf16* __restrict__ src, bf16* __restrict__ dst) {
    int b = blockIdx.z;
    int j0 = blockIdx.x * 64, d0 = blockIdx.y * 64;
    __shared__ short Ts[64][72];
    const bf16* S = src + (size_t)b * W_ * D_;
    bf16* Dd = dst + (size_t)b * W_ * D_;
    int tid = threadIdx.x;
    int r = tid >> 3, c = (tid & 7) * 8;
#pragma unroll
    for (int p = 0; p < 2; ++p) {
        int j = r + p * 32;
        bf16x8 vv = *(const bf16x8*)&S[(size_t)(j0 + j) * D_ + d0 + c];
#pragma unroll
        for (int e = 0; e < 8; ++e) Ts[j][c + e] = vv[e];
    }
    __syncthreads();
#pragma unroll
    for (int p = 0; p < 2; ++p) {
        int d = r + p * 32;
        bf16x8 vv;
#pragma unroll
        for (int e = 0; e < 8; ++e) vv[e] = Ts[c + e][d];
        *(bf16x8*)&Dd[(size_t)(d0 + d) * W_ + j0 + c] = vv;
    }
}

// ---------------------------------------------------------------------------
// qk epilogue: sum SK=4 fp32 partials, l2norm halves, gamma^{+/-i} -> qg, kg.
// ---------------------------------------------------------------------------
__global__ __launch_bounds__(128)
void qk_epilogue_kernel(const float* __restrict__ qkraw,
                        const float* __restrict__ decay_logit,
                        float* __restrict__ qg, float* __restrict__ kg) {
    int row = blockIdx.x;          // b*W + i
    int i = row & (W_ - 1);
    int t = threadIdx.x;
    int r = t & 63;
    bool isK = t >= 64;
    const size_t PS = (size_t)B_ * W_ * 128;   // partial stride
    size_t off = (size_t)row * 128 + t;
    float val = qkraw[off] + qkraw[PS + off] + qkraw[2 * PS + off] + qkraw[3 * PS + off];
    float sq = val * val;
#pragma unroll
    for (int o = 32; o; o >>= 1) sq += __shfl_xor(sq, o, 64);
    val = val / fmaxf(sqrtf(sq), 1e-8f);

    float dl = decay_logit[r];
    float gamma = 0.15f + 0.85f * (1.f / (1.f + expf(-dl)));
    float lg = logf(gamma);
    float e = isK ? expf(-(float)i * lg) : expf((float)i * lg);
    float o = val * e;
    if (isK) kg[(size_t)row * R_ + r] = o;
    else     qg[(size_t)row * R_ + r] = o;
}

// ---------------------------------------------------------------------------
// buildM v2: M[b,i,j] = (j<=i) ? gate*k_base + alpha*qg.kg : 0
// 64x64 tiles, float4 LDS reads, skip-without-write tiles tj > (ti|1)
// (provably unread by step 4's causal k-truncation).
// ---------------------------------------------------------------------------
__global__ __launch_bounds__(256)
void buildM_kernel(const float* __restrict__ qg, const float* __restrict__ kg,
                   const float* __restrict__ k_base,
                   const float* __restrict__ gate_logit,
                   const float* __restrict__ alpha_logit,
                   bf16* __restrict__ M) {
    int b = blockIdx.z;
    int ti = blockIdx.y, tj = blockIdx.x;   // 64-row/col tiles
    if (tj > (ti | 1)) return;              // never read by step 4: no write
    int i0 = ti * 64, j0 = tj * 64;
    bf16* Mb = M + (size_t)b * W_ * W_;
    int tid = threadIdx.x;

    if (tj > ti) {
        int row = tid >> 2, c0 = (tid & 3) * 16;
        bf16x8 z;
#pragma unroll
        for (int e = 0; e < 8; ++e) z[e] = 0;
        *(bf16x8*)&Mb[(size_t)(i0 + row) * W_ + j0 + c0] = z;
        *(bf16x8*)&Mb[(size_t)(i0 + row) * W_ + j0 + c0 + 8] = z;
        return;
    }

    __shared__ float Qs[64][68];
    __shared__ float Ks[64][68];
#pragma unroll
    for (int e = 0; e < 4; ++e) {
        int idx = tid + e * 256;            // float4 slot 0..1023
        int row = idx >> 4, c4 = (idx & 15) * 4;
        *(float4*)&Qs[row][c4] = *(const float4*)&qg[((size_t)b * W_ + i0 + row) * R_ + c4];
        *(float4*)&Ks[row][c4] = *(const float4*)&kg[((size_t)b * W_ + j0 + row) * R_ + c4];
    }
    __syncthreads();

    int tx = tid & 15, ty = tid >> 4;       // 4 cols, 4 rows per thread
    float acc[4][4] = {};
#pragma unroll 4
    for (int rq = 0; rq < 16; ++rq) {
        float4 qa[4], kb[4];
#pragma unroll
        for (int a = 0; a < 4; ++a) qa[a] = *(const float4*)&Qs[ty * 4 + a][rq * 4];
#pragma unroll
        for (int c = 0; c < 4; ++c) kb[c] = *(const float4*)&Ks[tx * 4 + c][rq * 4];
#pragma unroll
        for (int a = 0; a < 4; ++a)
#pragma unroll
            for (int c = 0; c < 4; ++c)
                acc[a][c] += qa[a].x * kb[c].x + qa[a].y * kb[c].y
                           + qa[a].z * kb[c].z + qa[a].w * kb[c].w;
    }

    float gate  = 1.f / (1.f + expf(-(*gate_logit)));
    float alpha = 1.f / (1.f + expf(-(*alpha_logit)));  // ALPHA_CAP = 1
#pragma unroll
    for (int a = 0; a < 4; ++a) {
        int i = i0 + ty * 4 + a;
        int jb = j0 + tx * 4;
        float4 vkb = *(const float4*)&k_base[(size_t)i * W_ + jb];
        short4v o;
        o[0] = (jb + 0 <= i) ? f2bs(gate * vkb.x + alpha * acc[a][0]) : (short)0;
        o[1] = (jb + 1 <= i) ? f2bs(gate * vkb.y + alpha * acc[a][1]) : (short)0;
        o[2] = (jb + 2 <= i) ? f2bs(gate * vkb.z + alpha * acc[a][2]) : (short)0;
        o[3] = (jb + 3 <= i) ? f2bs(gate * vkb.w + alpha * acc[a][3]) : (short)0;
        *(short4v*)&Mb[(size_t)i * W_ + jb] = o;
    }
}

// ---------------------------------------------------------------------------
// shared GEMM helpers
// ---------------------------------------------------------------------------
#define BAR() do { __builtin_amdgcn_sched_barrier(0); \
                   __builtin_amdgcn_s_barrier(); \
                   __builtin_amdgcn_sched_barrier(0); } while (0)

__device__ __forceinline__ void mfma8(const bf16x8 (&fa)[2], const bf16x8 (&fb)[4],
                                      f32x4 (&acc)[2][4]) {
#pragma unroll
    for (int mi = 0; mi < 2; ++mi)
#pragma unroll
        for (int ni = 0; ni < 4; ++ni)
            acc[mi][ni] = __builtin_amdgcn_mfma_f32_16x16x32_bf16(
                fa[mi], fb[ni], acc[mi][ni], 0, 0, 0);
}

__device__ __forceinline__ void readf(const short* At0, const short* Bt0, int slot,
                                      const int (&ao)[2], const int (&bo)[4],
                                      bf16x8 (&fa)[2], bf16x8 (&fb)[4]) {
    const short* Ard = At0 + slot * 4096;
    const short* Brd = Bt0 + slot * 4096;
#pragma unroll
    for (int mi = 0; mi < 2; ++mi) fa[mi] = *(const bf16x8*)&Ard[ao[mi]];
#pragma unroll
    for (int ni = 0; ni < 4; ++ni) fb[ni] = *(const bf16x8*)&Brd[bo[ni]];
}

// ---------------------------------------------------------------------------
// 128x128 8-wave MFMA GEMM, 5-slot ring — r15 geometry (proven best).
// *** Round-22 change: LOOP CHOICE BY K-DEPTH (template<PAIR>).
// Evidence r21: the pair loop (1 vmcnt+barrier per 2 K-tiles) gave
// 59.7->54.2us on long-K steps 5/7/8 (nIter 32/64), but the causal step 4
// regressed (66us outlier, FETCH 33.3, same signature as r7's imbalance
// outlier): short-K blocks (nIter 4-32, P as low as 2) pay the pair
// prologue's unoverlapped vmcnt(0) (~900cyc) and its shallower 2-tile
// depth over too few pairs. Step 2 (SK=4, nIter=8/chunk) has the same
// shape. Fix: PAIR=1 (r21 pair loop) for long-K non-causal steps 5/7/8;
// PAIR=0 (r15/r8 depth-3 counted-vmcnt + frag-prefetch loop, proven on
// short K through r8) for steps 2 and 4. Geometry/swizzle/staging/
// epilogue/r20-mirror identical in both.
// PAIR=0 loop: prologue stages tiles 0-3, vmcnt(6); iter t: vmcnt(4),
//   BAR, stage t+3, mfma(frags t), prefetch frags t+1; tail vmcnt 4/2/0.
// PAIR=1 loop: pair p: vmcnt(0) [pair p's 4 loads, issued one pair-body
//   earlier], BAR, stage pair p+1, read+mfma 2p, read+mfma 2p+1.
//   Slot audit r21: stage slots differ from read slots by 2 mod 5 != 0.
// r20 causal stripe-mirror kept (balanced 36 block-iters/CU on step 4).
// EPI 0: bf16 = acc (batched via z*sC) | EPI 1: fp32 = acc+bias+Res |
// EPI 2: bf16 = gelu(acc+bias)         | EPI 5: fp32 partial at z*sC.
// ---------------------------------------------------------------------------
template<int EPI, int SK, int PAIR>
__global__ __launch_bounds__(512, 4)
void mgemm_kernel(const bf16* __restrict__ A, const bf16* __restrict__ Bm,
                  const float* __restrict__ Res, const float* __restrict__ bias,
                  void* __restrict__ Cout,
                  int M, int N, int K,
                  long sA, long sB, long sC, int causal) {
    __shared__ __align__(16) short At[5][128 * 32];
    __shared__ __align__(16) short Bt[5][128 * 32];
    int z = blockIdx.z;
    const bf16* Ab = (SK > 1) ? A : A + (size_t)z * sA;
    const bf16* Bb = (SK > 1) ? Bm : Bm + (size_t)z * sB;
    int kchunk = K / SK;
    int kbeg = (SK > 1) ? z * kchunk : 0;
    int bx = blockIdx.x;
    if (SK == 1 && causal && z >= (int)(gridDim.z >> 1))
        bx = (int)gridDim.x - 1 - bx;        // r20: mirror stripe, balance pair
    int m0 = bx * 128, n0 = blockIdx.y * 128;
    int tid = threadIdx.x;
    int lane = tid & 63, wave = tid >> 6;
    int wy = wave >> 1, wx = wave & 1;
    int quad = lane >> 4, l15 = lane & 15;

    f32x4 acc[2][4];
#pragma unroll
    for (int i = 0; i < 2; ++i)
#pragma unroll
        for (int j = 0; j < 4; ++j)
            acc[i][j] = (f32x4){0.f, 0.f, 0.f, 0.f};

    int kend = kbeg + kchunk;
    if (SK == 1 && causal) kend = (m0 + 128 < K) ? m0 + 128 : K;
    int nIter = (kend - kbeg) >> 5;          // even, >= 4

    int srcChunk = ((lane & 3) ^ ((lane >> 3) & 3)) * 8;
    size_t rowA = (size_t)(m0 + wave * 16 + (lane >> 2)) * K;
    size_t rowB = (size_t)(n0 + wave * 16 + (lane >> 2)) * K;
    const bf16* aP = Ab + rowA + srcChunk + kbeg;
    const bf16* bP = Bb + rowB + srcChunk + kbeg;
    short* aDst = &At[0][0] + wave * 512;
    short* bDst = &Bt[0][0] + wave * 512;

    int rswz = (quad ^ ((l15 >> 1) & 3)) * 8;
    int ao[2], bo[4];
#pragma unroll
    for (int mi = 0; mi < 2; ++mi) ao[mi] = (wy * 32 + mi * 16 + l15) * 32 + rswz;
#pragma unroll
    for (int ni = 0; ni < 4; ++ni) bo[ni] = (wx * 64 + ni * 16 + l15) * 32 + rswz;

    if constexpr (PAIR == 0) {
        // ---- r15/r8 depth-3 loop (proven for short K: steps 2, 4) ----
#pragma unroll
        for (int p = 0; p < 4; ++p) {
            async16(aP, aDst + p * 4096);
            async16(bP, bDst + p * 4096);
            aP += 32; bP += 32;
        }
        asm volatile("s_waitcnt vmcnt(6)" ::: "memory");
        BAR();

        bf16x8 fa0[2], fb0[4], fa1[2], fb1[4];
        readf(&At[0][0], &Bt[0][0], 0, ao, bo, fa0, fb0);

        int sStage = 4;
        int sPf = 1;
        int nMain = nIter - 4;

        for (int t = 0; t < nMain; t += 2) {
            asm volatile("s_waitcnt vmcnt(4)" ::: "memory");
            BAR();
            async16(aP, aDst + sStage * 4096);
            async16(bP, bDst + sStage * 4096);
            aP += 32; bP += 32;
            sStage = (sStage == 4) ? 0 : sStage + 1;
            mfma8(fa0, fb0, acc);
            readf(&At[0][0], &Bt[0][0], sPf, ao, bo, fa1, fb1);
            sPf = (sPf == 4) ? 0 : sPf + 1;
            asm volatile("s_waitcnt vmcnt(4)" ::: "memory");
            BAR();
            async16(aP, aDst + sStage * 4096);
            async16(bP, bDst + sStage * 4096);
            aP += 32; bP += 32;
            sStage = (sStage == 4) ? 0 : sStage + 1;
            mfma8(fa1, fb1, acc);
            readf(&At[0][0], &Bt[0][0], sPf, ao, bo, fa0, fb0);
            sPf = (sPf == 4) ? 0 : sPf + 1;
        }

        asm volatile("s_waitcnt vmcnt(4)" ::: "memory");
        BAR();
        mfma8(fa0, fb0, acc);
        readf(&At[0][0], &Bt[0][0], sPf, ao, bo, fa1, fb1);
        sPf = (sPf == 4) ? 0 : sPf + 1;

        asm volatile("s_waitcnt vmcnt(2)" ::: "memory");
        BAR();
        mfma8(fa1, fb1, acc);
        readf(&At[0][0], &Bt[0][0], sPf, ao, bo, fa0, fb0);
        sPf = (sPf == 4) ? 0 : sPf + 1;

        asm volatile("s_waitcnt vmcnt(0)" ::: "memory");
        BAR();
        mfma8(fa0, fb0, acc);
        readf(&At[0][0], &Bt[0][0], sPf, ao, bo, fa1, fb1);

        mfma8(fa1, fb1, acc);
    } else {
        // ---- r21 pair loop (proven for long K: steps 5, 7, 8) ----
        int P = nIter >> 1;

        async16(aP, aDst);          async16(bP, bDst);          aP += 32; bP += 32;
        async16(aP, aDst + 4096);   async16(bP, bDst + 4096);   aP += 32; bP += 32;

        int sStage = 2;
        int sCur = 0;
        bf16x8 fa0[2], fb0[4], fa1[2], fb1[4];

        for (int p = 0; p < P; ++p) {
            asm volatile("s_waitcnt vmcnt(0)" ::: "memory");
            BAR();                               // publishes tiles 2p, 2p+1
            if (p + 1 < P) {                     // stage pair p+1
                async16(aP, aDst + sStage * 4096);
                async16(bP, bDst + sStage * 4096);
                aP += 32; bP += 32;
                sStage = (sStage == 4) ? 0 : sStage + 1;
                async16(aP, aDst + sStage * 4096);
                async16(bP, bDst + sStage * 4096);
                aP += 32; bP += 32;
                sStage = (sStage == 4) ? 0 : sStage + 1;
            }
            readf(&At[0][0], &Bt[0][0], sCur, ao, bo, fa0, fb0);
            mfma8(fa0, fb0, acc);
            sCur = (sCur == 4) ? 0 : sCur + 1;
            readf(&At[0][0], &Bt[0][0], sCur, ao, bo, fa1, fb1);
            mfma8(fa1, fb1, acc);
            sCur = (sCur == 4) ? 0 : sCur + 1;
        }
    }

    // ---- epilogue ----
#pragma unroll
    for (int ni = 0; ni < 4; ++ni) {
        int col = n0 + wx * 64 + ni * 16 + l15;
        float bv = (EPI == 1 || EPI == 2) ? bias[col] : 0.f;
#pragma unroll
        for (int mi = 0; mi < 2; ++mi) {
            int row0 = m0 + wy * 32 + mi * 16 + quad * 4;
#pragma unroll
            for (int r = 0; r < 4; ++r) {
                size_t idx = (size_t)(row0 + r) * N + col;
                float val = acc[mi][ni][r];
                if constexpr (EPI == 0) {
                    ((bf16*)Cout)[(size_t)z * sC + idx] = __float2bfloat16(val);
                } else if constexpr (EPI == 1) {
                    ((float*)Cout)[idx] = val + bv + Res[idx];
                } else if constexpr (EPI == 2) {
                    val += bv;
                    val = 0.5f * val * (1.f + erff(val * 0.70710678118654752f));
                    ((bf16*)Cout)[idx] = __float2bfloat16(val);
                } else {
                    ((float*)Cout)[(size_t)z * sC + idx] = val;
                }
            }
        }
    }
}

// ---------------------------------------------------------------------------
// Workspace (peak 62 MB):
//   [0,16)  : hnorm bf16 -> attn bf16 (step4 out) -> mnorm bf16 (step6 out)
//   [16,18) : uvT bf16 (dead after step 2) -> qg fp32 (written step 2b)
//   [18,20) : kg fp32
//   [20,36) : hnormT bf16            -+ tbuf bf16 [20,52) after step 4
//   [36,52) : qkraw fp32 4x4MB split-K partials (dead after 2b) -> Mbuf bf16
//   [52,54) : proj_w bf16   [54,58): up_w bf16   [58,62): down_w bf16
//   h1 lives in d_out (fp32); step 8 does same-index RMW (alias-safe).
// ---------------------------------------------------------------------------
extern "C" void kernel_launch(void* const* d_in, const int* in_sizes, int n_in,
                              void* d_out, int out_size, void* d_ws, size_t ws_size,
                              hipStream_t stream) {
    const float* h           = (const float*)d_in[0];
    const float* k_base      = (const float*)d_in[1];
    const float* decay_logit = (const float*)d_in[2];
    const float* gate_logit  = (const float*)d_in[3];
    const float* alpha_logit = (const float*)d_in[4];
    const float* u           = (const float*)d_in[5];
    const float* v           = (const float*)d_in[6];
    const float* proj_w      = (const float*)d_in[7];
    const float* proj_b      = (const float*)d_in[8];
    const float* norm1_scale = (const float*)d_in[9];
    const float* norm2_scale = (const float*)d_in[10];
    const float* up_w        = (const float*)d_in[11];
    const float* up_b        = (const float*)d_in[12];
    const float* down_w      = (const float*)d_in[13];
    const float* down_b      = (const float*)d_in[14];

    const size_t MB = 1048576;
    char* ws = (char*)d_ws;
    bf16*  hnorm   = (bf16*)(ws);                  // 16 MB
    bf16*  uvT     = (bf16*)(ws + 16 * MB);        // 256 KB (dead after step 2)
    float* qg      = (float*)(ws + 16 * MB);       //  2 MB (written step 2b)
    float* kg      = (float*)(ws + 18 * MB);       //  2 MB
    bf16*  hnormT  = (bf16*)(ws + 20 * MB);        // 16 MB
    float* qkraw   = (float*)(ws + 36 * MB);       // 16 MB partials (pre-buildM)
    bf16*  Mbuf    = (bf16*)(ws + 36 * MB);        // 16 MB (step 3 out)
    bf16*  proj_wb = (bf16*)(ws + 52 * MB);        //  2 MB
    bf16*  up_wb   = (bf16*)(ws + 54 * MB);        //  4 MB
    bf16*  down_wb = (bf16*)(ws + 58 * MB);        //  4 MB
    bf16*  attn    = hnorm;                        // [0,16) after qk GEMM
    bf16*  mnorm   = hnorm;
    bf16*  tbuf    = hnormT;                       // [20,52) after step 4
    float* h1      = (float*)d_out;

    // 0+1. fused prep: weight converts + uvT + rmsnorm(h) in ONE launch
    prep_kernel<<<2560 + 32 + B_ * W_, 256, 0, stream>>>(
        proj_w, up_w, down_w, proj_wb, up_wb, down_wb,
        u, v, uvT, h, norm1_scale, hnorm);

    // 1b. hnormT[b][d][j] = hnorm[b][j][d]
    transpose_kernel<<<dim3(W_ / 64, D_ / 64, B_), 256, 0, stream>>>(hnorm, hnormT);

    // 2. qkraw[z] = hnorm @ [u|v] K-chunk z (split-K=4; short-K -> PAIR=0)
    mgemm_kernel<5, 4, 0><<<dim3(B_ * W_ / 128, 1, 4), 512, 0, stream>>>(
        hnorm, uvT, nullptr, nullptr, qkraw, B_ * W_, 128, D_,
        0, 0, (long)B_ * W_ * 128, 0);

    // 2b. sum partials, l2norm halves, gamma^{+/-i} -> qg, kg (fp32)
    qk_epilogue_kernel<<<B_ * W_, 128, 0, stream>>>(qkraw, decay_logit, qg, kg);

    // 3. M = causal * (gate*k_base + alpha*scores)  [64x64 tiles, skip-unread]
    buildM_kernel<<<dim3(W_ / 64, W_ / 64, B_), 256, 0, stream>>>(
        qg, kg, k_base, gate_logit, alpha_logit, Mbuf);

    // 4. attn = M @ hnorm  (causal k-trunc, stripe-mirrored; short-K -> PAIR=0)
    mgemm_kernel<0, 1, 0><<<dim3(W_ / 128, D_ / 128, B_), 512, 0, stream>>>(
        Mbuf, hnormT, nullptr, nullptr, attn, W_, D_, W_,
        (long)W_ * W_, (long)W_ * D_, (long)W_ * D_, 1);

    // 5. h1 = h + attn @ proj_w^T + proj_b   -> d_out (fp32)  [PAIR=1]
    mgemm_kernel<1, 1, 1><<<dim3(B_ * W_ / 128, D_ / 128, 1), 512, 0, stream>>>(
        attn, proj_wb, h, proj_b, h1, B_ * W_, D_, D_, 0, 0, 0, 0);

    // 6. mnorm = rmsnorm(h1, norm2_scale)
    rmsnorm_kernel<<<B_ * W_, 256, 0, stream>>>(h1, norm2_scale, mnorm);

    // 7. t = gelu(mnorm @ up_w^T + up_b)     -> tbuf (bf16)  [PAIR=1]
    mgemm_kernel<2, 1, 1><<<dim3(B_ * W_ / 128, 2 * D_ / 128, 1), 512, 0, stream>>>(
        mnorm, up_wb, nullptr, up_b, tbuf, B_ * W_, 2 * D_, D_, 0, 0, 0, 0);

    // 8. out = h1 + t @ down_w^T + down_b  (h1 aliases d_out)  [PAIR=1]
    mgemm_kernel<1, 1, 1><<<dim3(B_ * W_ / 128, D_ / 128, 1), 512, 0, stream>>>(
        tbuf, down_wb, h1, down_b, (float*)d_out, B_ * W_, D_, 2 * D_, 0, 0, 0, 0);
}